// Round 3
// baseline (104.025 us; speedup 1.0000x reference)
//
#include <hip/hip_runtime.h>

// loss = (1/N) * sum_over_2x2_blocks [ sum(d^2) - 0.25*(sum d)^2 ],  d = sr - hr
// Derivation: Haar DWT2 is orthonormal; synth-of-one-subband + sum-of-squares
// preserves subband energy; LH^2+HL^2+HH^2 = |d|^2 - LL^2 per block (Parseval).
//
// Single fused kernel: per-block partials + last-block-done final reduction
// (deterministic: final sum order is fixed by partial index, independent of
// which block happens to finish last).

static constexpr unsigned long long N_TOTAL = 8ULL * 3ULL * 1024ULL * 1024ULL; // 25,165,824
static constexpr int ROW_W   = 1024;            // image width (floats)
static constexpr int N_ITEMS = 12288 * 256;     // (row-pairs) * (float4 segs per row)
static constexpr int BLOCKS  = 2048;            // exactly fills 256 CU * 8 blk/CU
static constexpr int THREADS = 256;
static constexpr int STRIDE  = BLOCKS * THREADS;   // 524288
static constexpr int ITERS   = N_ITEMS / STRIDE;   // exactly 6

__global__ __launch_bounds__(256) void whf_fused(const float* __restrict__ sr,
                                                 const float* __restrict__ hr,
                                                 float* __restrict__ partial,
                                                 unsigned int* __restrict__ counter,
                                                 float* __restrict__ out) {
    const int tid = blockIdx.x * THREADS + threadIdx.x;

    float acc0 = 0.0f, acc1 = 0.0f, acc2 = 0.0f, acc3 = 0.0f;

    #pragma unroll
    for (int it = 0; it < ITERS; ++it) {
        const int k = tid + it * STRIDE;         // compile-time-known stride
        const int p = k >> 8;                    // row-pair index (rows 2p, 2p+1)
        const int seg = k & 255;                 // float4 segment within the row
        const size_t i0 = (size_t)p * (2 * ROW_W) + (size_t)seg * 4;
        const float4 s0 = *reinterpret_cast<const float4*>(sr + i0);
        const float4 s1 = *reinterpret_cast<const float4*>(sr + i0 + ROW_W);
        const float4 h0 = *reinterpret_cast<const float4*>(hr + i0);
        const float4 h1 = *reinterpret_cast<const float4*>(hr + i0 + ROW_W);

        // block A: cols {0,1}
        float d00 = s0.x - h0.x, d01 = s0.y - h0.y;
        float d10 = s1.x - h1.x, d11 = s1.y - h1.y;
        float s = d00 + d01 + d10 + d11;
        float q = d00 * d00 + d01 * d01 + d10 * d10 + d11 * d11;
        if (it & 1) acc0 += q - 0.25f * s * s; else acc1 += q - 0.25f * s * s;

        // block B: cols {2,3}
        d00 = s0.z - h0.z; d01 = s0.w - h0.w;
        d10 = s1.z - h1.z; d11 = s1.w - h1.w;
        s = d00 + d01 + d10 + d11;
        q = d00 * d00 + d01 * d01 + d10 * d10 + d11 * d11;
        if (it & 1) acc2 += q - 0.25f * s * s; else acc3 += q - 0.25f * s * s;
    }

    float acc = (acc0 + acc2) + (acc1 + acc3);

    // wave64 shuffle reduction
    #pragma unroll
    for (int off = 32; off > 0; off >>= 1)
        acc += __shfl_down(acc, off, 64);

    __shared__ float smem[4];
    __shared__ bool is_last;
    const int lane = threadIdx.x & 63;
    const int wid = threadIdx.x >> 6;
    if (lane == 0) smem[wid] = acc;
    __syncthreads();
    if (threadIdx.x == 0) {
        partial[blockIdx.x] = (smem[0] + smem[1]) + (smem[2] + smem[3]);
        __threadfence();                                    // publish partial (device scope)
        unsigned int prev = atomicAdd(counter, 1u);         // device-scope by default
        is_last = (prev == (unsigned int)(BLOCKS - 1));
    }
    __syncthreads();

    if (is_last) {
        __threadfence();   // acquire: make all published partials visible
        double dacc = 0.0;
        for (int i = threadIdx.x; i < BLOCKS; i += THREADS)
            dacc += (double)partial[i];
        #pragma unroll
        for (int off = 32; off > 0; off >>= 1)
            dacc += __shfl_down(dacc, off, 64);

        __shared__ double dsm[4];
        if (lane == 0) dsm[wid] = dacc;
        __syncthreads();
        if (threadIdx.x == 0)
            out[0] = (float)((((dsm[0] + dsm[1]) + (dsm[2] + dsm[3])) / (double)N_TOTAL));
    }
}

extern "C" void kernel_launch(void* const* d_in, const int* in_sizes, int n_in,
                              void* d_out, int out_size, void* d_ws, size_t ws_size,
                              hipStream_t stream) {
    const float* sr = (const float*)d_in[0];
    const float* hr = (const float*)d_in[1];
    float* out = (float*)d_out;
    float* partial = (float*)d_ws;                              // 2048 floats = 8 KiB
    unsigned int* counter = (unsigned int*)((char*)d_ws + BLOCKS * sizeof(float));

    hipMemsetAsync(counter, 0, sizeof(unsigned int), stream);   // capture-safe reset
    whf_fused<<<BLOCKS, THREADS, 0, stream>>>(sr, hr, partial, counter, out);
}

// Round 4
// 38.109 us; speedup vs baseline: 2.7296x; 2.7296x over previous
//
#include <hip/hip_runtime.h>

// loss = (1/N) * sum_over_2x2_blocks [ sum(d^2) - 0.25*(sum d)^2 ],  d = sr - hr
// Derivation: Haar DWT2 is orthonormal; synth-of-one-subband + sum-of-squares
// preserves subband energy; LH^2+HL^2+HH^2 = |d|^2 - LL^2 per block (Parseval).
//
// Two-kernel structure (fused last-block-done version regressed 2.7x: 2048
// device-scope __threadfence()s force per-XCD L2 writebacks — see R3).
// This version clusters all 24 float4 loads per thread up-front for deep
// memory-level parallelism (R2 kept only ~4 in flight, VGPR=32).

static constexpr unsigned long long N_TOTAL = 8ULL * 3ULL * 1024ULL * 1024ULL; // 25,165,824
static constexpr int ROW_W   = 1024;            // image width (floats)
static constexpr int N_ITEMS = 12288 * 256;     // (row-pairs) * (float4 segs per row)
static constexpr int BLOCKS  = 2048;
static constexpr int THREADS = 256;
static constexpr int STRIDE  = BLOCKS * THREADS;   // 524288
static constexpr int ITERS   = N_ITEMS / STRIDE;   // exactly 6

// Note: STRIDE % 256 == 0, so seg = tid & 255 is iteration-invariant and
// p = (tid>>8) + it*2048  ->  i0 = base + it*(2048*ROW_W*2)/2 = base + it*4194304.
static constexpr size_t IT_OFF = (size_t)2048 * 2 * ROW_W;  // 4,194,304 floats = 16 MiB

__global__ __launch_bounds__(256) void whf_partial(const float* __restrict__ sr,
                                                   const float* __restrict__ hr,
                                                   float* __restrict__ partial) {
    const int tid = blockIdx.x * THREADS + threadIdx.x;
    const size_t base = (size_t)(tid >> 8) * (2 * ROW_W) + (size_t)(tid & 255) * 4;

    float4 S0[ITERS], S1[ITERS], H0[ITERS], H1[ITERS];

    // Issue all 24 loads before any compute: ~24-deep MLP per wave.
    #pragma unroll
    for (int it = 0; it < ITERS; ++it) {
        const size_t i0 = base + (size_t)it * IT_OFF;
        S0[it] = *reinterpret_cast<const float4*>(sr + i0);
        S1[it] = *reinterpret_cast<const float4*>(sr + i0 + ROW_W);
        H0[it] = *reinterpret_cast<const float4*>(hr + i0);
        H1[it] = *reinterpret_cast<const float4*>(hr + i0 + ROW_W);
    }

    float acc0 = 0.0f, acc1 = 0.0f;
    #pragma unroll
    for (int it = 0; it < ITERS; ++it) {
        // block A: cols {0,1}
        float d00 = S0[it].x - H0[it].x, d01 = S0[it].y - H0[it].y;
        float d10 = S1[it].x - H1[it].x, d11 = S1[it].y - H1[it].y;
        float s = d00 + d01 + d10 + d11;
        float q = d00 * d00 + d01 * d01 + d10 * d10 + d11 * d11;
        acc0 += q - 0.25f * s * s;

        // block B: cols {2,3}
        d00 = S0[it].z - H0[it].z; d01 = S0[it].w - H0[it].w;
        d10 = S1[it].z - H1[it].z; d11 = S1[it].w - H1[it].w;
        s = d00 + d01 + d10 + d11;
        q = d00 * d00 + d01 * d01 + d10 * d10 + d11 * d11;
        acc1 += q - 0.25f * s * s;
    }
    float acc = acc0 + acc1;

    // wave64 shuffle reduction
    #pragma unroll
    for (int off = 32; off > 0; off >>= 1)
        acc += __shfl_down(acc, off, 64);

    __shared__ float smem[4];
    const int lane = threadIdx.x & 63;
    const int wid = threadIdx.x >> 6;
    if (lane == 0) smem[wid] = acc;
    __syncthreads();
    if (threadIdx.x == 0)
        partial[blockIdx.x] = (smem[0] + smem[1]) + (smem[2] + smem[3]);
}

__global__ __launch_bounds__(256) void whf_final(const float* __restrict__ partial,
                                                 float* __restrict__ out) {
    // 256 threads, double accumulation over 2048 partials (deterministic)
    double acc = 0.0;
    for (int i = threadIdx.x; i < BLOCKS; i += 256)
        acc += (double)partial[i];
    #pragma unroll
    for (int off = 32; off > 0; off >>= 1)
        acc += __shfl_down(acc, off, 64);

    __shared__ double smem[4];
    const int lane = threadIdx.x & 63;
    const int wid = threadIdx.x >> 6;
    if (lane == 0) smem[wid] = acc;
    __syncthreads();
    if (threadIdx.x == 0)
        out[0] = (float)(((smem[0] + smem[1]) + (smem[2] + smem[3])) / (double)N_TOTAL);
}

extern "C" void kernel_launch(void* const* d_in, const int* in_sizes, int n_in,
                              void* d_out, int out_size, void* d_ws, size_t ws_size,
                              hipStream_t stream) {
    const float* sr = (const float*)d_in[0];
    const float* hr = (const float*)d_in[1];
    float* out = (float*)d_out;
    float* partial = (float*)d_ws;   // 2048 floats = 8 KiB scratch

    whf_partial<<<BLOCKS, THREADS, 0, stream>>>(sr, hr, partial);
    whf_final<<<1, 256, 0, stream>>>(partial, out);
}